// Round 1
// baseline (132.118 us; speedup 1.0000x reference)
//
#include <hip/hip_runtime.h>
#include <hip/hip_bf16.h>

using short8 = __attribute__((ext_vector_type(8))) short;
using f32x4  = __attribute__((ext_vector_type(4))) float;

constexpr int BSZ = 8192;
constexpr int DD  = 512;
constexpr int NC  = 100;
constexpr float INV_T = 1.0f / 0.07f;   // analytic row max = 1/T (diagonal)

static __device__ __forceinline__ ushort f2bf(float x) {
    union { float f; unsigned u; } c; c.f = x;
    unsigned r = c.u + 0x7fffu + ((c.u >> 16) & 1u);   // RNE
    return (ushort)(r >> 16);
}

static __device__ __forceinline__ void gload16(const void* g, void* l) {
    __builtin_amdgcn_global_load_lds((const __attribute__((address_space(1))) void*)g,
                                     (__attribute__((address_space(3))) void*)l, 16, 0, 0);
}

// ---------- kernel 1: L2-normalize rows, fp32 -> bf16 ----------
__global__ __launch_bounds__(256) void norm_rows(const float* __restrict__ feat,
                                                 ushort* __restrict__ fnrm) {
    const int row = blockIdx.x * 4 + (threadIdx.x >> 6);
    const int l   = threadIdx.x & 63;
    const float4* src = reinterpret_cast<const float4*>(feat + (size_t)row * DD);
    float4 v0 = src[l * 2 + 0];
    float4 v1 = src[l * 2 + 1];
    float ss = v0.x*v0.x + v0.y*v0.y + v0.z*v0.z + v0.w*v0.w
             + v1.x*v1.x + v1.y*v1.y + v1.z*v1.z + v1.w*v1.w;
    #pragma unroll
    for (int m = 32; m >= 1; m >>= 1) ss += __shfl_xor(ss, m, 64);
    const float rn = rsqrtf(ss);
    float vals[8] = {v0.x, v0.y, v0.z, v0.w, v1.x, v1.y, v1.z, v1.w};
    ushort u[8];
    #pragma unroll
    for (int j = 0; j < 8; ++j) u[j] = f2bf(vals[j] * rn);
    *reinterpret_cast<short8*>(fnrm + (size_t)row * DD + l * 8) =
        *reinterpret_cast<short8*>(u);
}

// ---------- kernel 2: label histogram (npos_i = hist[label_i] - 1) ----------
__global__ __launch_bounds__(256) void label_hist(const int* __restrict__ labels,
                                                  int* __restrict__ counts) {
    __shared__ int lc[NC];
    const int t = threadIdx.x;
    if (t < NC) lc[t] = 0;
    __syncthreads();
    for (int i = t; i < BSZ; i += 256) atomicAdd(&lc[labels[i]], 1);
    __syncthreads();
    if (t < NC) counts[t] = lc[t];
}

// ---------- kernel 3: fused sim-GEMM + exp/mask partial reduction ----------
// grid (64 colTiles, 64 rowTiles), 256 threads (4 waves, each wave = 32 rows x 128 cols)
__global__ __launch_bounds__(256) void supcon_main(const ushort* __restrict__ fnrm,
                                                   const int* __restrict__ labels,
                                                   float* __restrict__ part_denom,
                                                   float* __restrict__ part_spos) {
    __shared__ __align__(16) ushort a_lds[128 * 32];
    __shared__ __align__(16) ushort b_lds[128 * 32];
    __shared__ int lbl_row[128], lbl_col[128];

    const int t  = threadIdx.x;
    const int w  = t >> 6, l = t & 63;
    const int lr = l & 15, grp = l >> 4;
    const int ct = blockIdx.x, rt = blockIdx.y;
    const int rowBase = rt * 128, colBase = ct * 128;

    if (t < 128) { lbl_row[t] = labels[rowBase + t]; lbl_col[t] = labels[colBase + t]; }

    // staging: thread t loads 16B; tile is [128][32] bf16 row-major, 2 issues per tile
    const int srow = t >> 2, scol = (t & 3) << 3;
    const ushort* gA = fnrm + (size_t)(rowBase + srow) * DD + scol;
    const ushort* gB = fnrm + (size_t)(colBase + srow) * DD + scol;
    const size_t rstep = (size_t)64 * DD;
    ushort* ldsA0 = a_lds + w * 512;
    ushort* ldsA1 = a_lds + 2048 + w * 512;
    ushort* ldsB0 = b_lds + w * 512;
    ushort* ldsB1 = b_lds + 2048 + w * 512;

    f32x4 acc[2][8];
    #pragma unroll
    for (int i = 0; i < 2; ++i)
        #pragma unroll
        for (int j = 0; j < 8; ++j) acc[i][j] = f32x4{0.f, 0.f, 0.f, 0.f};

    for (int k0 = 0; k0 < DD; k0 += 32) {
        __syncthreads();                 // all waves done reading previous tile
        gload16(gA + k0,         ldsA0);
        gload16(gA + rstep + k0, ldsA1);
        gload16(gB + k0,         ldsB0);
        gload16(gB + rstep + k0, ldsB1);
        __syncthreads();                 // drains vmcnt -> LDS ready

        short8 aF[2], bF[8];
        #pragma unroll
        for (int fm = 0; fm < 2; ++fm)
            aF[fm] = *reinterpret_cast<const short8*>(
                &a_lds[(w * 32 + fm * 16 + lr) * 32 + grp * 8]);
        #pragma unroll
        for (int fq = 0; fq < 8; ++fq)
            bF[fq] = *reinterpret_cast<const short8*>(
                &b_lds[(fq * 16 + lr) * 32 + grp * 8]);
        #pragma unroll
        for (int fm = 0; fm < 2; ++fm)
            #pragma unroll
            for (int fq = 0; fq < 8; ++fq)
                acc[fm][fq] = __builtin_amdgcn_mfma_f32_16x16x32_bf16(
                    aF[fm], bF[fq], acc[fm][fq], 0, 0, 0);
    }

    // epilogue: sim = dot * INV_T; denom += exp(sim - INV_T) (j!=i);
    //           spos += sim where labels match (j!=i)
    #pragma unroll
    for (int fm = 0; fm < 2; ++fm) {
        #pragma unroll
        for (int r = 0; r < 4; ++r) {
            const int row_l = w * 32 + fm * 16 + grp * 4 + r;
            const int grow  = rowBase + row_l;
            const int lrow  = lbl_row[row_l];
            float dsum = 0.f, ssum = 0.f;
            #pragma unroll
            for (int fq = 0; fq < 8; ++fq) {
                const int col_l = fq * 16 + lr;
                const float sim = acc[fm][fq][r] * INV_T;
                const float e   = __expf(sim - INV_T);
                if ((colBase + col_l) != grow) {
                    dsum += e;
                    if (lbl_col[col_l] == lrow) ssum += sim;
                }
            }
            #pragma unroll
            for (int m = 8; m >= 1; m >>= 1) {
                dsum += __shfl_xor(dsum, m, 64);
                ssum += __shfl_xor(ssum, m, 64);
            }
            if (lr == 0) {   // unique writer per (colTile,row): deterministic
                part_denom[(size_t)ct * BSZ + grow] = dsum;
                part_spos [(size_t)ct * BSZ + grow] = ssum;
            }
        }
    }
}

// ---------- kernel 4: per-row finalize ----------
__global__ __launch_bounds__(256) void row_finalize(const float* __restrict__ part_denom,
                                                    const float* __restrict__ part_spos,
                                                    const int* __restrict__ counts,
                                                    const int* __restrict__ labels,
                                                    float* __restrict__ c_row,
                                                    float* __restrict__ v_row) {
    const int row = blockIdx.x * 256 + threadIdx.x;
    float denom = 0.f, spos = 0.f;
    for (int ctile = 0; ctile < 64; ++ctile) {
        denom += part_denom[(size_t)ctile * BSZ + row];
        spos  += part_spos [(size_t)ctile * BSZ + row];
    }
    const int   npos  = counts[labels[row]] - 1;
    const float npf   = (float)npos;
    const float mean  = (spos - npf * INV_T - npf * logf(denom + 1e-12f)) / (npf + 1e-12f);
    const bool  valid = npos > 0;
    c_row[row] = valid ? mean : 0.f;
    v_row[row] = valid ? 1.f : 0.f;
}

// ---------- kernel 5: final scalar reduce ----------
__global__ __launch_bounds__(1024) void final_reduce(const float* __restrict__ c_row,
                                                     const float* __restrict__ v_row,
                                                     float* __restrict__ out) {
    __shared__ float sdata[16], vdata[16];
    const int t = threadIdx.x;
    float s = 0.f, v = 0.f;
    for (int i = t; i < BSZ; i += 1024) { s += c_row[i]; v += v_row[i]; }
    #pragma unroll
    for (int m = 32; m >= 1; m >>= 1) { s += __shfl_xor(s, m, 64); v += __shfl_xor(v, m, 64); }
    if ((t & 63) == 0) { sdata[t >> 6] = s; vdata[t >> 6] = v; }
    __syncthreads();
    if (t == 0) {
        float st = 0.f, vt = 0.f;
        #pragma unroll
        for (int i = 0; i < 16; ++i) { st += sdata[i]; vt += vdata[i]; }
        out[0] = -st / fmaxf(vt, 1.f);
    }
}

extern "C" void kernel_launch(void* const* d_in, const int* in_sizes, int n_in,
                              void* d_out, int out_size, void* d_ws, size_t ws_size,
                              hipStream_t stream) {
    const float* feat   = (const float*)d_in[0];
    const int*   labels = (const int*)d_in[1];
    float*       out    = (float*)d_out;

    char* ws = (char*)d_ws;
    ushort* fnrm       = (ushort*)ws;  ws += (size_t)BSZ * DD * 2;   // 8 MB bf16 normalized
    float*  part_denom = (float*)ws;   ws += (size_t)64 * BSZ * 4;   // 2 MB
    float*  part_spos  = (float*)ws;   ws += (size_t)64 * BSZ * 4;   // 2 MB
    int*    counts     = (int*)ws;     ws += 512;
    float*  c_row      = (float*)ws;   ws += BSZ * 4;
    float*  v_row      = (float*)ws;   ws += BSZ * 4;

    hipLaunchKernelGGL(norm_rows,    dim3(BSZ / 4), dim3(256),  0, stream, feat, fnrm);
    hipLaunchKernelGGL(label_hist,   dim3(1),       dim3(256),  0, stream, labels, counts);
    hipLaunchKernelGGL(supcon_main,  dim3(64, 64),  dim3(256),  0, stream,
                       fnrm, labels, part_denom, part_spos);
    hipLaunchKernelGGL(row_finalize, dim3(BSZ/256), dim3(256),  0, stream,
                       part_denom, part_spos, counts, labels, c_row, v_row);
    hipLaunchKernelGGL(final_reduce, dim3(1),       dim3(1024), 0, stream, c_row, v_row, out);
}

// Round 2
// 120.116 us; speedup vs baseline: 1.0999x; 1.0999x over previous
//
#include <hip/hip_runtime.h>
#include <hip/hip_bf16.h>

using short8 = __attribute__((ext_vector_type(8))) short;
using f32x4  = __attribute__((ext_vector_type(4))) float;

constexpr int BSZ = 8192;
constexpr int DD  = 512;
constexpr int NC  = 100;
constexpr float INV_T = 1.0f / 0.07f;   // analytic row max = 1/T (diagonal)

static __device__ __forceinline__ ushort f2bf(float x) {
    union { float f; unsigned u; } c; c.f = x;
    unsigned r = c.u + 0x7fffu + ((c.u >> 16) & 1u);   // RNE
    return (ushort)(r >> 16);
}

static __device__ __forceinline__ void gload16(const void* g, void* l) {
    __builtin_amdgcn_global_load_lds((const __attribute__((address_space(1))) void*)g,
                                     (__attribute__((address_space(3))) void*)l, 16, 0, 0);
}

// ---------- kernel 1: L2-normalize rows, fp32 -> bf16 ----------
__global__ __launch_bounds__(256) void norm_rows(const float* __restrict__ feat,
                                                 ushort* __restrict__ fnrm) {
    const int row = blockIdx.x * 4 + (threadIdx.x >> 6);
    const int l   = threadIdx.x & 63;
    const float4* src = reinterpret_cast<const float4*>(feat + (size_t)row * DD);
    float4 v0 = src[l * 2 + 0];
    float4 v1 = src[l * 2 + 1];
    float ss = v0.x*v0.x + v0.y*v0.y + v0.z*v0.z + v0.w*v0.w
             + v1.x*v1.x + v1.y*v1.y + v1.z*v1.z + v1.w*v1.w;
    #pragma unroll
    for (int m = 32; m >= 1; m >>= 1) ss += __shfl_xor(ss, m, 64);
    const float rn = rsqrtf(ss);
    float vals[8] = {v0.x, v0.y, v0.z, v0.w, v1.x, v1.y, v1.z, v1.w};
    ushort u[8];
    #pragma unroll
    for (int j = 0; j < 8; ++j) u[j] = f2bf(vals[j] * rn);
    *reinterpret_cast<short8*>(fnrm + (size_t)row * DD + l * 8) =
        *reinterpret_cast<short8*>(u);
}

// ---------- kernel 2: label histogram (npos_i = hist[label_i] - 1) ----------
__global__ __launch_bounds__(256) void label_hist(const int* __restrict__ labels,
                                                  int* __restrict__ counts) {
    __shared__ int lc[NC];
    const int t = threadIdx.x;
    if (t < NC) lc[t] = 0;
    __syncthreads();
    for (int i = t; i < BSZ; i += 256) atomicAdd(&lc[labels[i]], 1);
    __syncthreads();
    if (t < NC) counts[t] = lc[t];
}

// ---------- kernel 3: fused sim-GEMM, upper-triangle only (symmetric) ----------
// grid (64 colTiles, 64 rowTiles); blocks with ct<rt exit immediately.
// Off-diagonal blocks emit BOTH row-side partials (slot [ct][rowBase..]) and
// col-side partials (slot [rt][colBase..]); diagonal blocks row-side only.
__global__ __launch_bounds__(256) void supcon_main(const ushort* __restrict__ fnrm,
                                                   const int* __restrict__ labels,
                                                   float* __restrict__ part_denom,
                                                   float* __restrict__ part_spos) {
    __shared__ __align__(16) ushort a_lds[128 * 32];
    __shared__ __align__(16) ushort b_lds[128 * 32];
    __shared__ int lbl_row[128], lbl_col[128];

    const int ct = blockIdx.x, rt = blockIdx.y;
    if (ct < rt) return;                 // upper triangle only (block-uniform)
    const bool diag = (ct == rt);

    const int t  = threadIdx.x;
    const int w  = t >> 6, l = t & 63;
    const int lr = l & 15, grp = l >> 4;
    const int rowBase = rt * 128, colBase = ct * 128;

    if (t < 128) { lbl_row[t] = labels[rowBase + t]; lbl_col[t] = labels[colBase + t]; }

    // staging: thread t fills physical 16B-chunk t (and 256+t). LDS dest is
    // linear (gload_lds requirement); the XOR swizzle (chunk c -> c^((c>>3)&3),
    // i.e. byte bits 4-5 ^= row bits 1-2) is applied by PRE-SWIZZLING the
    // global source, and again on the ds_read side.
    const int lc_  = t ^ ((t >> 3) & 3);        // logical chunk for physical chunk t
    const int srow = lc_ >> 2;
    const int scol = (lc_ & 3) << 3;            // ushort offset within row
    const ushort* gA = fnrm + (size_t)(rowBase + srow) * DD + scol;
    const ushort* gB = fnrm + (size_t)(colBase + srow) * DD + scol;
    const size_t rstep = (size_t)64 * DD;
    ushort* ldsA0 = a_lds + w * 512;
    ushort* ldsA1 = a_lds + 2048 + w * 512;
    ushort* ldsB0 = b_lds + w * 512;
    ushort* ldsB1 = b_lds + 2048 + w * 512;

    f32x4 acc[2][8];
    #pragma unroll
    for (int i = 0; i < 2; ++i)
        #pragma unroll
        for (int j = 0; j < 8; ++j) acc[i][j] = f32x4{0.f, 0.f, 0.f, 0.f};

    for (int k0 = 0; k0 < DD; k0 += 32) {
        __syncthreads();                 // all waves done reading previous tile
        gload16(gA + k0,         ldsA0);
        gload16(gA + rstep + k0, ldsA1);
        gload16(gB + k0,         ldsB0);
        gload16(gB + rstep + k0, ldsB1);
        __syncthreads();                 // drains vmcnt -> LDS ready

        short8 aF[2], bF[8];
        #pragma unroll
        for (int fm = 0; fm < 2; ++fm) {
            const int row = w * 32 + fm * 16 + lr;
            aF[fm] = *reinterpret_cast<const short8*>(
                &a_lds[row * 32 + ((grp ^ ((row >> 1) & 3)) << 3)]);
        }
        #pragma unroll
        for (int fq = 0; fq < 8; ++fq) {
            const int row = fq * 16 + lr;
            bF[fq] = *reinterpret_cast<const short8*>(
                &b_lds[row * 32 + ((grp ^ ((row >> 1) & 3)) << 3)]);
        }
        #pragma unroll
        for (int fm = 0; fm < 2; ++fm)
            #pragma unroll
            for (int fq = 0; fq < 8; ++fq)
                acc[fm][fq] = __builtin_amdgcn_mfma_f32_16x16x32_bf16(
                    aF[fm], bF[fq], acc[fm][fq], 0, 0, 0);
    }

    // ---- epilogue ----
    float cd[8], cs[8];
    #pragma unroll
    for (int fq = 0; fq < 8; ++fq) { cd[fq] = 0.f; cs[fq] = 0.f; }

    #pragma unroll
    for (int fm = 0; fm < 2; ++fm) {
        #pragma unroll
        for (int r = 0; r < 4; ++r) {
            const int row_l = w * 32 + fm * 16 + grp * 4 + r;
            const int grow  = rowBase + row_l;
            const int lrow  = lbl_row[row_l];
            float dsum = 0.f, ssum = 0.f;
            #pragma unroll
            for (int fq = 0; fq < 8; ++fq) {
                const int col_l = fq * 16 + lr;
                const float sim = acc[fm][fq][r] * INV_T;
                const float e   = __expf(sim - INV_T);
                const bool  pos = (lbl_col[col_l] == lrow);
                const bool  ok  = (colBase + col_l) != grow;   // self-exclude (diag only)
                const float ev  = ok ? e : 0.f;
                const float sv  = (ok && pos) ? sim : 0.f;
                dsum += ev; ssum += sv;
                if (!diag) { cd[fq] += ev; cs[fq] += sv; }
            }
            #pragma unroll
            for (int m = 8; m >= 1; m >>= 1) {
                dsum += __shfl_xor(dsum, m, 64);
                ssum += __shfl_xor(ssum, m, 64);
            }
            if (lr == 0) {   // unique writer per (colTile,row): deterministic
                part_denom[(size_t)ct * BSZ + grow] = dsum;
                part_spos [(size_t)ct * BSZ + grow] = ssum;
            }
        }
    }

    // ---- col-side partials (transposed contribution), off-diagonal only ----
    if (!diag) {
        // reduce over grp (rows within wave): lanes l and l^16/l^32 share lr
        #pragma unroll
        for (int fq = 0; fq < 8; ++fq) {
            cd[fq] += __shfl_xor(cd[fq], 16, 64);
            cd[fq] += __shfl_xor(cd[fq], 32, 64);
            cs[fq] += __shfl_xor(cs[fq], 16, 64);
            cs[fq] += __shfl_xor(cs[fq], 32, 64);
        }
        __syncthreads();                 // k-loop LDS reads done -> safe to reuse
        float* red = reinterpret_cast<float*>(a_lds);   // [2][4 waves][128 cols]
        if (grp == 0) {
            #pragma unroll
            for (int fq = 0; fq < 8; ++fq) {
                red[      w * 128 + fq * 16 + lr] = cd[fq];
                red[512 + w * 128 + fq * 16 + lr] = cs[fq];
            }
        }
        __syncthreads();
        if (t < 128) {
            const float d = red[t] + red[128 + t] + red[256 + t] + red[384 + t];
            const float s = red[512 + t] + red[640 + t] + red[768 + t] + red[896 + t];
            part_denom[(size_t)rt * BSZ + colBase + t] = d;
            part_spos [(size_t)rt * BSZ + colBase + t] = s;
        }
    }
}

// ---------- kernel 4: per-row finalize ----------
__global__ __launch_bounds__(256) void row_finalize(const float* __restrict__ part_denom,
                                                    const float* __restrict__ part_spos,
                                                    const int* __restrict__ counts,
                                                    const int* __restrict__ labels,
                                                    float* __restrict__ c_row,
                                                    float* __restrict__ v_row) {
    const int row = blockIdx.x * 256 + threadIdx.x;
    float denom = 0.f, spos = 0.f;
    for (int ctile = 0; ctile < 64; ++ctile) {
        denom += part_denom[(size_t)ctile * BSZ + row];
        spos  += part_spos [(size_t)ctile * BSZ + row];
    }
    const int   npos  = counts[labels[row]] - 1;
    const float npf   = (float)npos;
    const float mean  = (spos - npf * INV_T - npf * logf(denom + 1e-12f)) / (npf + 1e-12f);
    const bool  valid = npos > 0;
    c_row[row] = valid ? mean : 0.f;
    v_row[row] = valid ? 1.f : 0.f;
}

// ---------- kernel 5: final scalar reduce ----------
__global__ __launch_bounds__(1024) void final_reduce(const float* __restrict__ c_row,
                                                     const float* __restrict__ v_row,
                                                     float* __restrict__ out) {
    __shared__ float sdata[16], vdata[16];
    const int t = threadIdx.x;
    float s = 0.f, v = 0.f;
    for (int i = t; i < BSZ; i += 1024) { s += c_row[i]; v += v_row[i]; }
    #pragma unroll
    for (int m = 32; m >= 1; m >>= 1) { s += __shfl_xor(s, m, 64); v += __shfl_xor(v, m, 64); }
    if ((t & 63) == 0) { sdata[t >> 6] = s; vdata[t >> 6] = v; }
    __syncthreads();
    if (t == 0) {
        float st = 0.f, vt = 0.f;
        #pragma unroll
        for (int i = 0; i < 16; ++i) { st += sdata[i]; vt += vdata[i]; }
        out[0] = -st / fmaxf(vt, 1.f);
    }
}

extern "C" void kernel_launch(void* const* d_in, const int* in_sizes, int n_in,
                              void* d_out, int out_size, void* d_ws, size_t ws_size,
                              hipStream_t stream) {
    const float* feat   = (const float*)d_in[0];
    const int*   labels = (const int*)d_in[1];
    float*       out    = (float*)d_out;

    char* ws = (char*)d_ws;
    ushort* fnrm       = (ushort*)ws;  ws += (size_t)BSZ * DD * 2;   // 8 MB bf16 normalized
    float*  part_denom = (float*)ws;   ws += (size_t)64 * BSZ * 4;   // 2 MB
    float*  part_spos  = (float*)ws;   ws += (size_t)64 * BSZ * 4;   // 2 MB
    int*    counts     = (int*)ws;     ws += 512;
    float*  c_row      = (float*)ws;   ws += BSZ * 4;
    float*  v_row      = (float*)ws;   ws += BSZ * 4;

    hipLaunchKernelGGL(norm_rows,    dim3(BSZ / 4), dim3(256),  0, stream, feat, fnrm);
    hipLaunchKernelGGL(label_hist,   dim3(1),       dim3(256),  0, stream, labels, counts);
    hipLaunchKernelGGL(supcon_main,  dim3(64, 64),  dim3(256),  0, stream,
                       fnrm, labels, part_denom, part_spos);
    hipLaunchKernelGGL(row_finalize, dim3(BSZ/256), dim3(256),  0, stream,
                       part_denom, part_spos, counts, labels, c_row, v_row);
    hipLaunchKernelGGL(final_reduce, dim3(1),       dim3(1024), 0, stream, c_row, v_row, out);
}

// Round 3
// 102.760 us; speedup vs baseline: 1.2857x; 1.1689x over previous
//
#include <hip/hip_runtime.h>
#include <hip/hip_bf16.h>

using short8 = __attribute__((ext_vector_type(8))) short;
using f32x4  = __attribute__((ext_vector_type(4))) float;

constexpr int BSZ = 8192;
constexpr int DD  = 512;
constexpr int NC  = 100;
constexpr int NT  = 64;                 // 128-row tiles per dim
constexpr int NBLK = NT * (NT + 1) / 2; // 2080 upper-triangle blocks
constexpr float INV_T = 1.0f / 0.07f;   // analytic row max = 1/T (diagonal)

static __device__ __forceinline__ ushort f2bf(float x) {
    union { float f; unsigned u; } c; c.f = x;
    unsigned r = c.u + 0x7fffu + ((c.u >> 16) & 1u);   // RNE
    return (ushort)(r >> 16);
}

static __device__ __forceinline__ void gload16(const void* g, void* l) {
    __builtin_amdgcn_global_load_lds((const __attribute__((address_space(1))) void*)g,
                                     (__attribute__((address_space(3))) void*)l, 16, 0, 0);
}

// ---------- kernel 1: L2-normalize rows, fp32 -> bf16 ----------
__global__ __launch_bounds__(256) void norm_rows(const float* __restrict__ feat,
                                                 ushort* __restrict__ fnrm) {
    const int row = blockIdx.x * 4 + (threadIdx.x >> 6);
    const int l   = threadIdx.x & 63;
    const float4* src = reinterpret_cast<const float4*>(feat + (size_t)row * DD);
    float4 v0 = src[l * 2 + 0];
    float4 v1 = src[l * 2 + 1];
    float ss = v0.x*v0.x + v0.y*v0.y + v0.z*v0.z + v0.w*v0.w
             + v1.x*v1.x + v1.y*v1.y + v1.z*v1.z + v1.w*v1.w;
    #pragma unroll
    for (int m = 32; m >= 1; m >>= 1) ss += __shfl_xor(ss, m, 64);
    const float rn = rsqrtf(ss);
    float vals[8] = {v0.x, v0.y, v0.z, v0.w, v1.x, v1.y, v1.z, v1.w};
    ushort u[8];
    #pragma unroll
    for (int j = 0; j < 8; ++j) u[j] = f2bf(vals[j] * rn);
    *reinterpret_cast<short8*>(fnrm + (size_t)row * DD + l * 8) =
        *reinterpret_cast<short8*>(u);
}

// ---------- kernel 2: label histogram (npos_i = hist[label_i] - 1) ----------
__global__ __launch_bounds__(256) void label_hist(const int* __restrict__ labels,
                                                  int* __restrict__ counts) {
    __shared__ int lc[NC];
    const int t = threadIdx.x;
    if (t < NC) lc[t] = 0;
    __syncthreads();
    for (int i = t; i < BSZ; i += 256) atomicAdd(&lc[labels[i]], 1);
    __syncthreads();
    if (t < NC) counts[t] = lc[t];
}

// ---------- kernel 3: fused sim-GEMM, upper-triangle only, dbuf prefetch ----------
// linear grid of 2080 blocks -> (rt, ct) with ct >= rt.
// Off-diagonal blocks emit BOTH row-side partials (slot [ct][rowBase..]) and
// col-side partials (slot [rt][colBase..]); diagonal blocks row-side only.
__global__ __launch_bounds__(256) void supcon_main(const ushort* __restrict__ fnrm,
                                                   const int* __restrict__ labels,
                                                   float* __restrict__ part_denom,
                                                   float* __restrict__ part_spos) {
    __shared__ __align__(16) ushort a_lds[2][128 * 32];
    __shared__ __align__(16) ushort b_lds[2][128 * 32];
    __shared__ int lbl_row[128], lbl_col[128];

    // decode linear block id -> upper-triangle (rt, ct)
    int rt = 0, base = 0;
    {
        const int bid = blockIdx.x;
        while (base + (NT - rt) <= bid) { base += NT - rt; ++rt; }
        base = rt + (bid - base);        // ct
    }
    const int ct = base;
    const bool diag = (ct == rt);

    const int t  = threadIdx.x;
    const int w  = t >> 6, l = t & 63;
    const int lr = l & 15, grp = l >> 4;
    const int rowBase = rt * 128, colBase = ct * 128;

    if (t < 128) { lbl_row[t] = labels[rowBase + t]; lbl_col[t] = labels[colBase + t]; }

    // staging: thread t fills physical 16B-chunk t (and 256+t). LDS dest is
    // linear (gload_lds requirement); the XOR swizzle (chunk c -> c^((c>>3)&3),
    // i.e. byte bits 4-5 ^= row bits 1-2) is applied by PRE-SWIZZLING the
    // global source, and again on the ds_read side.
    const int lc_  = t ^ ((t >> 3) & 3);        // logical chunk for physical chunk t
    const int srow = lc_ >> 2;
    const int scol = (lc_ & 3) << 3;            // ushort offset within row
    const ushort* gA = fnrm + (size_t)(rowBase + srow) * DD + scol;
    const ushort* gB = fnrm + (size_t)(colBase + srow) * DD + scol;
    const size_t rstep = (size_t)64 * DD;

    f32x4 acc[2][8];
    #pragma unroll
    for (int i = 0; i < 2; ++i)
        #pragma unroll
        for (int j = 0; j < 8; ++j) acc[i][j] = f32x4{0.f, 0.f, 0.f, 0.f};

    // prologue: stage k-tile 0 into buffer 0
    {
        ushort* A = a_lds[0] + w * 512;
        ushort* B = b_lds[0] + w * 512;
        gload16(gA,         A);
        gload16(gA + rstep, A + 2048);
        gload16(gB,         B);
        gload16(gB + rstep, B + 2048);
    }

    int p = 0;
    for (int it = 0; it < DD / 32; ++it) {
        __syncthreads();   // drains stage into buf[p] (vmcnt0); prior reads of buf[p^1] done
        if (it + 1 < DD / 32) {          // prefetch next k-tile into buf[p^1]
            const int k0 = (it + 1) * 32;
            ushort* A = a_lds[p ^ 1] + w * 512;
            ushort* B = b_lds[p ^ 1] + w * 512;
            gload16(gA + k0,         A);
            gload16(gA + rstep + k0, A + 2048);
            gload16(gB + k0,         B);
            gload16(gB + rstep + k0, B + 2048);
        }

        short8 aF[2], bF[8];
        #pragma unroll
        for (int fm = 0; fm < 2; ++fm) {
            const int row = w * 32 + fm * 16 + lr;
            aF[fm] = *reinterpret_cast<const short8*>(
                &a_lds[p][row * 32 + ((grp ^ ((row >> 1) & 3)) << 3)]);
        }
        #pragma unroll
        for (int fq = 0; fq < 8; ++fq) {
            const int row = fq * 16 + lr;
            bF[fq] = *reinterpret_cast<const short8*>(
                &b_lds[p][row * 32 + ((grp ^ ((row >> 1) & 3)) << 3)]);
        }
        #pragma unroll
        for (int fm = 0; fm < 2; ++fm)
            #pragma unroll
            for (int fq = 0; fq < 8; ++fq)
                acc[fm][fq] = __builtin_amdgcn_mfma_f32_16x16x32_bf16(
                    aF[fm], bF[fq], acc[fm][fq], 0, 0, 0);
        p ^= 1;
    }

    // ---- epilogue ----
    float cd[8], cs[8];
    #pragma unroll
    for (int fq = 0; fq < 8; ++fq) { cd[fq] = 0.f; cs[fq] = 0.f; }

    #pragma unroll
    for (int fm = 0; fm < 2; ++fm) {
        #pragma unroll
        for (int r = 0; r < 4; ++r) {
            const int row_l = w * 32 + fm * 16 + grp * 4 + r;
            const int grow  = rowBase + row_l;
            const int lrow  = lbl_row[row_l];
            float dsum = 0.f, ssum = 0.f;
            #pragma unroll
            for (int fq = 0; fq < 8; ++fq) {
                const int col_l = fq * 16 + lr;
                const float sim = acc[fm][fq][r] * INV_T;
                const float e   = __expf(sim - INV_T);
                const bool  pos = (lbl_col[col_l] == lrow);
                const bool  ok  = (colBase + col_l) != grow;   // self-exclude (diag only)
                const float ev  = ok ? e : 0.f;
                const float sv  = (ok && pos) ? sim : 0.f;
                dsum += ev; ssum += sv;
                if (!diag) { cd[fq] += ev; cs[fq] += sv; }
            }
            #pragma unroll
            for (int m = 8; m >= 1; m >>= 1) {
                dsum += __shfl_xor(dsum, m, 64);
                ssum += __shfl_xor(ssum, m, 64);
            }
            if (lr == 0) {   // unique writer per (colTile,row): deterministic
                part_denom[(size_t)ct * BSZ + grow] = dsum;
                part_spos [(size_t)ct * BSZ + grow] = ssum;
            }
        }
    }

    // ---- col-side partials (transposed contribution), off-diagonal only ----
    if (!diag) {
        #pragma unroll
        for (int fq = 0; fq < 8; ++fq) {
            cd[fq] += __shfl_xor(cd[fq], 16, 64);
            cd[fq] += __shfl_xor(cd[fq], 32, 64);
            cs[fq] += __shfl_xor(cs[fq], 16, 64);
            cs[fq] += __shfl_xor(cs[fq], 32, 64);
        }
        __syncthreads();                 // k-loop LDS reads done -> safe to reuse
        float* red = reinterpret_cast<float*>(&a_lds[0][0]);   // [2][4 waves][128 cols]
        if (grp == 0) {
            #pragma unroll
            for (int fq = 0; fq < 8; ++fq) {
                red[      w * 128 + fq * 16 + lr] = cd[fq];
                red[512 + w * 128 + fq * 16 + lr] = cs[fq];
            }
        }
        __syncthreads();
        if (t < 128) {
            const float d = red[t] + red[128 + t] + red[256 + t] + red[384 + t];
            const float s = red[512 + t] + red[640 + t] + red[768 + t] + red[896 + t];
            part_denom[(size_t)rt * BSZ + colBase + t] = d;
            part_spos [(size_t)rt * BSZ + colBase + t] = s;
        }
    }
}

// ---------- kernel 4: per-row finalize ----------
__global__ __launch_bounds__(256) void row_finalize(const float* __restrict__ part_denom,
                                                    const float* __restrict__ part_spos,
                                                    const int* __restrict__ counts,
                                                    const int* __restrict__ labels,
                                                    float* __restrict__ c_row,
                                                    float* __restrict__ v_row) {
    const int row = blockIdx.x * 256 + threadIdx.x;
    float denom = 0.f, spos = 0.f;
    for (int ctile = 0; ctile < 64; ++ctile) {
        denom += part_denom[(size_t)ctile * BSZ + row];
        spos  += part_spos [(size_t)ctile * BSZ + row];
    }
    const int   npos  = counts[labels[row]] - 1;
    const float npf   = (float)npos;
    const float mean  = (spos - npf * INV_T - npf * logf(denom + 1e-12f)) / (npf + 1e-12f);
    const bool  valid = npos > 0;
    c_row[row] = valid ? mean : 0.f;
    v_row[row] = valid ? 1.f : 0.f;
}

// ---------- kernel 5: final scalar reduce ----------
__global__ __launch_bounds__(1024) void final_reduce(const float* __restrict__ c_row,
                                                     const float* __restrict__ v_row,
                                                     float* __restrict__ out) {
    __shared__ float sdata[16], vdata[16];
    const int t = threadIdx.x;
    float s = 0.f, v = 0.f;
    for (int i = t; i < BSZ; i += 1024) { s += c_row[i]; v += v_row[i]; }
    #pragma unroll
    for (int m = 32; m >= 1; m >>= 1) { s += __shfl_xor(s, m, 64); v += __shfl_xor(v, m, 64); }
    if ((t & 63) == 0) { sdata[t >> 6] = s; vdata[t >> 6] = v; }
    __syncthreads();
    if (t == 0) {
        float st = 0.f, vt = 0.f;
        #pragma unroll
        for (int i = 0; i < 16; ++i) { st += sdata[i]; vt += vdata[i]; }
        out[0] = -st / fmaxf(vt, 1.f);
    }
}

extern "C" void kernel_launch(void* const* d_in, const int* in_sizes, int n_in,
                              void* d_out, int out_size, void* d_ws, size_t ws_size,
                              hipStream_t stream) {
    const float* feat   = (const float*)d_in[0];
    const int*   labels = (const int*)d_in[1];
    float*       out    = (float*)d_out;

    char* ws = (char*)d_ws;
    ushort* fnrm       = (ushort*)ws;  ws += (size_t)BSZ * DD * 2;   // 8 MB bf16 normalized
    float*  part_denom = (float*)ws;   ws += (size_t)64 * BSZ * 4;   // 2 MB
    float*  part_spos  = (float*)ws;   ws += (size_t)64 * BSZ * 4;   // 2 MB
    int*    counts     = (int*)ws;     ws += 512;
    float*  c_row      = (float*)ws;   ws += BSZ * 4;
    float*  v_row      = (float*)ws;   ws += BSZ * 4;

    hipLaunchKernelGGL(norm_rows,    dim3(BSZ / 4), dim3(256),  0, stream, feat, fnrm);
    hipLaunchKernelGGL(label_hist,   dim3(1),       dim3(256),  0, stream, labels, counts);
    hipLaunchKernelGGL(supcon_main,  dim3(NBLK),    dim3(256),  0, stream,
                       fnrm, labels, part_denom, part_spos);
    hipLaunchKernelGGL(row_finalize, dim3(BSZ/256), dim3(256),  0, stream,
                       part_denom, part_spos, counts, labels, c_row, v_row);
    hipLaunchKernelGGL(final_reduce, dim3(1),       dim3(1024), 0, stream, c_row, v_row, out);
}

// Round 4
// 98.545 us; speedup vs baseline: 1.3407x; 1.0428x over previous
//
#include <hip/hip_runtime.h>
#include <hip/hip_bf16.h>

using short8 = __attribute__((ext_vector_type(8))) short;
using f32x4  = __attribute__((ext_vector_type(4))) float;

constexpr int BSZ = 8192;
constexpr int DD  = 512;
constexpr int NC  = 100;
constexpr int NT  = 64;                 // 128-row tiles per dim
constexpr int NBLK = NT * (NT + 1) / 2; // 2080 upper-triangle blocks
constexpr int KIT  = DD / 32;           // 16 k-iterations
constexpr float INV_T = 1.0f / 0.07f;   // analytic row max = 1/T (diagonal)

static __device__ __forceinline__ ushort f2bf(float x) {
    union { float f; unsigned u; } c; c.f = x;
    unsigned r = c.u + 0x7fffu + ((c.u >> 16) & 1u);   // RNE
    return (ushort)(r >> 16);
}

static __device__ __forceinline__ void gload16(const void* g, void* l) {
    __builtin_amdgcn_global_load_lds((const __attribute__((address_space(1))) void*)g,
                                     (__attribute__((address_space(3))) void*)l, 16, 0, 0);
}

// ---------- kernel 1: L2-normalize rows, fp32 -> bf16 ----------
__global__ __launch_bounds__(256) void norm_rows(const float* __restrict__ feat,
                                                 ushort* __restrict__ fnrm) {
    const int row = blockIdx.x * 4 + (threadIdx.x >> 6);
    const int l   = threadIdx.x & 63;
    const float4* src = reinterpret_cast<const float4*>(feat + (size_t)row * DD);
    float4 v0 = src[l * 2 + 0];
    float4 v1 = src[l * 2 + 1];
    float ss = v0.x*v0.x + v0.y*v0.y + v0.z*v0.z + v0.w*v0.w
             + v1.x*v1.x + v1.y*v1.y + v1.z*v1.z + v1.w*v1.w;
    #pragma unroll
    for (int m = 32; m >= 1; m >>= 1) ss += __shfl_xor(ss, m, 64);
    const float rn = rsqrtf(ss);
    float vals[8] = {v0.x, v0.y, v0.z, v0.w, v1.x, v1.y, v1.z, v1.w};
    ushort u[8];
    #pragma unroll
    for (int j = 0; j < 8; ++j) u[j] = f2bf(vals[j] * rn);
    *reinterpret_cast<short8*>(fnrm + (size_t)row * DD + l * 8) =
        *reinterpret_cast<short8*>(u);
}

// ---------- kernel 2: label histogram (npos_i = hist[label_i] - 1) ----------
__global__ __launch_bounds__(256) void label_hist(const int* __restrict__ labels,
                                                  int* __restrict__ counts) {
    __shared__ int lc[NC];
    const int t = threadIdx.x;
    if (t < NC) lc[t] = 0;
    __syncthreads();
    for (int i = t; i < BSZ; i += 256) atomicAdd(&lc[labels[i]], 1);
    __syncthreads();
    if (t < NC) counts[t] = lc[t];
}

// ---------- kernel 3: fused sim-GEMM, upper-tri, depth-2 counted-vmcnt pipeline ----
// linear grid of 2080 blocks -> (rt, ct) with ct >= rt.
// 3 LDS buffers; per iter: vmcnt(4) [tile 'it' landed, tiles it+1..it+2 stay
// in flight across the raw barrier] -> s_barrier -> issue tile it+2 -> compute.
__global__ __launch_bounds__(256) void supcon_main(const ushort* __restrict__ fnrm,
                                                   const int* __restrict__ labels,
                                                   float* __restrict__ part_denom,
                                                   float* __restrict__ part_spos) {
    __shared__ __align__(16) ushort a_lds[3][128 * 32];
    __shared__ __align__(16) ushort b_lds[3][128 * 32];
    __shared__ int lbl_row[128], lbl_col[128];

    // decode linear block id -> upper-triangle (rt, ct)
    int rt = 0, base = 0;
    {
        const int bid = blockIdx.x;
        while (base + (NT - rt) <= bid) { base += NT - rt; ++rt; }
        base = rt + (bid - base);        // ct
    }
    const int ct = base;
    const bool diag = (ct == rt);

    const int t  = threadIdx.x;
    const int w  = t >> 6, l = t & 63;
    const int lr = l & 15, grp = l >> 4;
    const int rowBase = rt * 128, colBase = ct * 128;

    if (t < 128) { lbl_row[t] = labels[rowBase + t]; lbl_col[t] = labels[colBase + t]; }

    // staging: thread t fills physical 16B-chunk t (and 256+t). LDS dest is
    // linear (gload_lds requirement); the XOR swizzle (chunk c -> c^((c>>3)&3))
    // is applied by PRE-SWIZZLING the global source, and again on ds_read.
    const int lc_  = t ^ ((t >> 3) & 3);        // logical chunk for physical chunk t
    const int srow = lc_ >> 2;
    const int scol = (lc_ & 3) << 3;            // ushort offset within row
    const ushort* gA = fnrm + (size_t)(rowBase + srow) * DD + scol;
    const ushort* gB = fnrm + (size_t)(colBase + srow) * DD + scol;
    const size_t rstep = (size_t)64 * DD;

    f32x4 acc[2][8];
    #pragma unroll
    for (int i = 0; i < 2; ++i)
        #pragma unroll
        for (int j = 0; j < 8; ++j) acc[i][j] = f32x4{0.f, 0.f, 0.f, 0.f};

    auto stage = [&](int tile, int buf) {
        const int k0 = tile * 32;
        ushort* A = a_lds[buf] + w * 512;
        ushort* B = b_lds[buf] + w * 512;
        gload16(gA + k0,         A);
        gload16(gA + rstep + k0, A + 2048);
        gload16(gB + k0,         B);
        gload16(gB + rstep + k0, B + 2048);
    };

    // prologue: tiles 0,1 in flight (8 vmem ops/thread)
    stage(0, 0);
    stage(1, 1);

    int p = 0;                           // buffer holding tile 'it'
    for (int it = 0; it < KIT; ++it) {
        if (it < KIT - 1) asm volatile("s_waitcnt vmcnt(4)" ::: "memory");
        else              asm volatile("s_waitcnt vmcnt(0)" ::: "memory");
        __builtin_amdgcn_s_barrier();    // raw: in-flight prefetch NOT drained
        asm volatile("" ::: "memory");
        if (it < KIT - 2) {
            const int q = (p >= 1) ? p - 1 : 2;   // (it+2)%3 == (it-1)%3
            stage(it + 2, q);
        }

        const ushort* Ab = a_lds[p];
        const ushort* Bb = b_lds[p];
        short8 aF[2], bF[8];
        #pragma unroll
        for (int fm = 0; fm < 2; ++fm) {
            const int row = w * 32 + fm * 16 + lr;
            aF[fm] = *reinterpret_cast<const short8*>(
                &Ab[row * 32 + ((grp ^ ((row >> 1) & 3)) << 3)]);
        }
        #pragma unroll
        for (int fq = 0; fq < 8; ++fq) {
            const int row = fq * 16 + lr;
            bF[fq] = *reinterpret_cast<const short8*>(
                &Bb[row * 32 + ((grp ^ ((row >> 1) & 3)) << 3)]);
        }
        #pragma unroll
        for (int fm = 0; fm < 2; ++fm)
            #pragma unroll
            for (int fq = 0; fq < 8; ++fq)
                acc[fm][fq] = __builtin_amdgcn_mfma_f32_16x16x32_bf16(
                    aF[fm], bF[fq], acc[fm][fq], 0, 0, 0);
        p = (p == 2) ? 0 : p + 1;
    }

    // ---- epilogue ----
    float cd[8], cs[8];
    #pragma unroll
    for (int fq = 0; fq < 8; ++fq) { cd[fq] = 0.f; cs[fq] = 0.f; }

    #pragma unroll
    for (int fm = 0; fm < 2; ++fm) {
        #pragma unroll
        for (int r = 0; r < 4; ++r) {
            const int row_l = w * 32 + fm * 16 + grp * 4 + r;
            const int grow  = rowBase + row_l;
            const int lrow  = lbl_row[row_l];
            float dsum = 0.f, ssum = 0.f;
            #pragma unroll
            for (int fq = 0; fq < 8; ++fq) {
                const int col_l = fq * 16 + lr;
                const float sim = acc[fm][fq][r] * INV_T;
                const float e   = __expf(sim - INV_T);
                const bool  pos = (lbl_col[col_l] == lrow);
                const bool  ok  = (colBase + col_l) != grow;   // self-exclude (diag only)
                const float ev  = ok ? e : 0.f;
                const float sv  = (ok && pos) ? sim : 0.f;
                dsum += ev; ssum += sv;
                if (!diag) { cd[fq] += ev; cs[fq] += sv; }
            }
            #pragma unroll
            for (int m = 8; m >= 1; m >>= 1) {
                dsum += __shfl_xor(dsum, m, 64);
                ssum += __shfl_xor(ssum, m, 64);
            }
            if (lr == 0) {   // unique writer per (colTile,row): deterministic
                part_denom[(size_t)ct * BSZ + grow] = dsum;
                part_spos [(size_t)ct * BSZ + grow] = ssum;
            }
        }
    }

    // ---- col-side partials (transposed contribution), off-diagonal only ----
    if (!diag) {
        #pragma unroll
        for (int fq = 0; fq < 8; ++fq) {
            cd[fq] += __shfl_xor(cd[fq], 16, 64);
            cd[fq] += __shfl_xor(cd[fq], 32, 64);
            cs[fq] += __shfl_xor(cs[fq], 16, 64);
            cs[fq] += __shfl_xor(cs[fq], 32, 64);
        }
        __syncthreads();                 // k-loop LDS reads done -> safe to reuse
        float* red = reinterpret_cast<float*>(&a_lds[0][0]);   // [2][4 waves][128 cols]
        if (grp == 0) {
            #pragma unroll
            for (int fq = 0; fq < 8; ++fq) {
                red[      w * 128 + fq * 16 + lr] = cd[fq];
                red[512 + w * 128 + fq * 16 + lr] = cs[fq];
            }
        }
        __syncthreads();
        if (t < 128) {
            const float d = red[t] + red[128 + t] + red[256 + t] + red[384 + t];
            const float s = red[512 + t] + red[640 + t] + red[768 + t] + red[896 + t];
            part_denom[(size_t)rt * BSZ + colBase + t] = d;
            part_spos [(size_t)rt * BSZ + colBase + t] = s;
        }
    }
}

// ---------- kernel 4: per-row finalize ----------
__global__ __launch_bounds__(256) void row_finalize(const float* __restrict__ part_denom,
                                                    const float* __restrict__ part_spos,
                                                    const int* __restrict__ counts,
                                                    const int* __restrict__ labels,
                                                    float* __restrict__ c_row,
                                                    float* __restrict__ v_row) {
    const int row = blockIdx.x * 256 + threadIdx.x;
    float denom = 0.f, spos = 0.f;
    for (int ctile = 0; ctile < 64; ++ctile) {
        denom += part_denom[(size_t)ctile * BSZ + row];
        spos  += part_spos [(size_t)ctile * BSZ + row];
    }
    const int   npos  = counts[labels[row]] - 1;
    const float npf   = (float)npos;
    const float mean  = (spos - npf * INV_T - npf * logf(denom + 1e-12f)) / (npf + 1e-12f);
    const bool  valid = npos > 0;
    c_row[row] = valid ? mean : 0.f;
    v_row[row] = valid ? 1.f : 0.f;
}

// ---------- kernel 5: final scalar reduce ----------
__global__ __launch_bounds__(1024) void final_reduce(const float* __restrict__ c_row,
                                                     const float* __restrict__ v_row,
                                                     float* __restrict__ out) {
    __shared__ float sdata[16], vdata[16];
    const int t = threadIdx.x;
    float s = 0.f, v = 0.f;
    for (int i = t; i < BSZ; i += 1024) { s += c_row[i]; v += v_row[i]; }
    #pragma unroll
    for (int m = 32; m >= 1; m >>= 1) { s += __shfl_xor(s, m, 64); v += __shfl_xor(v, m, 64); }
    if ((t & 63) == 0) { sdata[t >> 6] = s; vdata[t >> 6] = v; }
    __syncthreads();
    if (t == 0) {
        float st = 0.f, vt = 0.f;
        #pragma unroll
        for (int i = 0; i < 16; ++i) { st += sdata[i]; vt += vdata[i]; }
        out[0] = -st / fmaxf(vt, 1.f);
    }
}

extern "C" void kernel_launch(void* const* d_in, const int* in_sizes, int n_in,
                              void* d_out, int out_size, void* d_ws, size_t ws_size,
                              hipStream_t stream) {
    const float* feat   = (const float*)d_in[0];
    const int*   labels = (const int*)d_in[1];
    float*       out    = (float*)d_out;

    char* ws = (char*)d_ws;
    ushort* fnrm       = (ushort*)ws;  ws += (size_t)BSZ * DD * 2;   // 8 MB bf16 normalized
    float*  part_denom = (float*)ws;   ws += (size_t)64 * BSZ * 4;   // 2 MB
    float*  part_spos  = (float*)ws;   ws += (size_t)64 * BSZ * 4;   // 2 MB
    int*    counts     = (int*)ws;     ws += 512;
    float*  c_row      = (float*)ws;   ws += BSZ * 4;
    float*  v_row      = (float*)ws;   ws += BSZ * 4;

    hipLaunchKernelGGL(norm_rows,    dim3(BSZ / 4), dim3(256),  0, stream, feat, fnrm);
    hipLaunchKernelGGL(label_hist,   dim3(1),       dim3(256),  0, stream, labels, counts);
    hipLaunchKernelGGL(supcon_main,  dim3(NBLK),    dim3(256),  0, stream,
                       fnrm, labels, part_denom, part_spos);
    hipLaunchKernelGGL(row_finalize, dim3(BSZ/256), dim3(256),  0, stream,
                       part_denom, part_spos, counts, labels, c_row, v_row);
    hipLaunchKernelGGL(final_reduce, dim3(1),       dim3(1024), 0, stream, c_row, v_row, out);
}

// Round 5
// 98.460 us; speedup vs baseline: 1.3418x; 1.0009x over previous
//
#include <hip/hip_runtime.h>
#include <hip/hip_bf16.h>

using short8 = __attribute__((ext_vector_type(8))) short;
using f32x4  = __attribute__((ext_vector_type(4))) float;

constexpr int BSZ = 8192;
constexpr int DD  = 512;
constexpr int NC  = 100;
constexpr int NT  = 64;                 // 128-row tiles per dim
constexpr int NBLK = NT * (NT + 1) / 2; // 2080 upper-triangle blocks
constexpr int KIT  = DD / 64;           // 8 k-iterations (BK=64)
constexpr float INV_T = 1.0f / 0.07f;   // analytic row max = 1/T (diagonal)

static __device__ __forceinline__ ushort f2bf(float x) {
    union { float f; unsigned u; } c; c.f = x;
    unsigned r = c.u + 0x7fffu + ((c.u >> 16) & 1u);   // RNE
    return (ushort)(r >> 16);
}

static __device__ __forceinline__ void gload16(const void* g, void* l) {
    __builtin_amdgcn_global_load_lds((const __attribute__((address_space(1))) void*)g,
                                     (__attribute__((address_space(3))) void*)l, 16, 0, 0);
}

// ---------- kernel 1: L2-normalize rows, fp32 -> bf16 ----------
__global__ __launch_bounds__(256) void norm_rows(const float* __restrict__ feat,
                                                 ushort* __restrict__ fnrm) {
    const int row = blockIdx.x * 4 + (threadIdx.x >> 6);
    const int l   = threadIdx.x & 63;
    const float4* src = reinterpret_cast<const float4*>(feat + (size_t)row * DD);
    float4 v0 = src[l * 2 + 0];
    float4 v1 = src[l * 2 + 1];
    float ss = v0.x*v0.x + v0.y*v0.y + v0.z*v0.z + v0.w*v0.w
             + v1.x*v1.x + v1.y*v1.y + v1.z*v1.z + v1.w*v1.w;
    #pragma unroll
    for (int m = 32; m >= 1; m >>= 1) ss += __shfl_xor(ss, m, 64);
    const float rn = rsqrtf(ss);
    float vals[8] = {v0.x, v0.y, v0.z, v0.w, v1.x, v1.y, v1.z, v1.w};
    ushort u[8];
    #pragma unroll
    for (int j = 0; j < 8; ++j) u[j] = f2bf(vals[j] * rn);
    *reinterpret_cast<short8*>(fnrm + (size_t)row * DD + l * 8) =
        *reinterpret_cast<short8*>(u);
}

// ---------- kernel 2: label histogram (npos_i = hist[label_i] - 1) ----------
__global__ __launch_bounds__(256) void label_hist(const int* __restrict__ labels,
                                                  int* __restrict__ counts) {
    __shared__ int lc[NC];
    const int t = threadIdx.x;
    if (t < NC) lc[t] = 0;
    __syncthreads();
    for (int i = t; i < BSZ; i += 256) atomicAdd(&lc[labels[i]], 1);
    __syncthreads();
    if (t < NC) counts[t] = lc[t];
}

// ---------- kernel 3: fused sim-GEMM, upper-tri, BK=64, 2-phase pipeline ----------
// linear grid of 2080 blocks -> (rt, ct) with ct >= rt. 4 waves in 2x2 grid,
// each wave owns a 64x64 output sub-tile. Fully unrolled K-loop (all LDS/stage
// addressing compile-time). 2 LDS buffers, counted prologue, vmcnt(0)+barrier
// one compute-phase after each stage issue.
__global__ __launch_bounds__(256) void supcon_main(const ushort* __restrict__ fnrm,
                                                   const int* __restrict__ labels,
                                                   float* __restrict__ part_denom,
                                                   float* __restrict__ part_spos) {
    // [buf][A=0/B=1][128 rows][64 cols] bf16 = 64 KB; XOR-swizzled chunks.
    __shared__ __align__(16) ushort smem[2 * 2 * 8192];
    __shared__ int lbl_row[128], lbl_col[128];

    // decode linear block id -> upper-triangle (rt, ct)
    int rt = 0, base = 0;
    {
        const int bid = blockIdx.x;
        while (base + (NT - rt) <= bid) { base += NT - rt; ++rt; }
        base = rt + (bid - base);        // ct
    }
    const int ct = base;
    const bool diag = (ct == rt);

    const int t  = threadIdx.x;
    const int w  = t >> 6, l = t & 63;
    const int lr = l & 15, grp = l >> 4;
    const int wr = w >> 1, wc = w & 1;   // 2x2 wave grid
    const int rowBase = rt * 128, colBase = ct * 128;

    if (t < 128) { lbl_row[t] = labels[rowBase + t]; lbl_col[t] = labels[colBase + t]; }

    // --- staging pointers: thread t fills physical 16B chunks p = w*64+l+j*256
    // of each [128][64] tile. Swizzle: logical chunk-in-row = phys ^ (row&7);
    // applied by pre-swizzling the global source (LDS dest stays linear).
    const ushort* gsA[4]; const ushort* gsB[4];
    #pragma unroll
    for (int j = 0; j < 4; ++j) {
        const int p   = w * 64 + l + j * 256;
        const int row = p >> 3;
        const int ccl = (p & 7) ^ (row & 7);
        gsA[j] = fnrm + (size_t)(rowBase + row) * DD + ccl * 8;
        gsB[j] = fnrm + (size_t)(colBase + row) * DD + ccl * 8;
    }

    // --- ds_read frag byte-addresses (loop-invariant; buf/frag add immediates)
    // frag(row0, ksub): lane reads row=row0+lr, chunk (ksub*4+grp)^(row&7).
    int adsA[2], adsB[2];
    #pragma unroll
    for (int ks = 0; ks < 2; ++ks) {
        adsA[ks] = (wr * 64 + lr) * 128 + (((ks * 4 + grp) ^ (lr & 7)) << 4);
        adsB[ks] = 16384 + (wc * 64 + lr) * 128 + (((ks * 4 + grp) ^ (lr & 7)) << 4);
    }
    const char* smb = (const char*)smem;

    f32x4 acc[4][4];
    #pragma unroll
    for (int i = 0; i < 4; ++i)
        #pragma unroll
        for (int j = 0; j < 4; ++j) acc[i][j] = f32x4{0.f, 0.f, 0.f, 0.f};

    #define STAGE(it, b)                                                          \
        {   _Pragma("unroll")                                                     \
            for (int j = 0; j < 4; ++j)                                           \
                gload16(gsA[j] + (it) * 64, smem + (b) * 16384 + w * 512 + j * 2048); \
            _Pragma("unroll")                                                     \
            for (int j = 0; j < 4; ++j)                                           \
                gload16(gsB[j] + (it) * 64, smem + (b) * 16384 + 8192 + w * 512 + j * 2048); }

    #define COMPUTE(b)                                                            \
        {   _Pragma("unroll")                                                     \
            for (int ks = 0; ks < 2; ++ks) {                                      \
                short8 aF[4], bF[4];                                              \
                _Pragma("unroll")                                                 \
                for (int f = 0; f < 4; ++f)                                       \
                    aF[f] = *reinterpret_cast<const short8*>(                     \
                        smb + (b) * 32768 + adsA[ks] + f * 2048);                 \
                _Pragma("unroll")                                                 \
                for (int f = 0; f < 4; ++f)                                       \
                    bF[f] = *reinterpret_cast<const short8*>(                     \
                        smb + (b) * 32768 + adsB[ks] + f * 2048);                 \
                _Pragma("unroll")                                                 \
                for (int fa = 0; fa < 4; ++fa)                                    \
                    _Pragma("unroll")                                             \
                    for (int fb = 0; fb < 4; ++fb)                                \
                        acc[fa][fb] = __builtin_amdgcn_mfma_f32_16x16x32_bf16(    \
                            aF[fa], bF[fb], acc[fa][fb], 0, 0, 0);                \
            } }

    // prologue: tiles 0,1 both in flight; wait only for tile 0 (8 newer allowed)
    STAGE(0, 0)
    STAGE(1, 1)
    asm volatile("s_waitcnt vmcnt(8)" ::: "memory");
    __builtin_amdgcn_s_barrier();

    #pragma unroll
    for (int it = 0; it < KIT; ++it) {
        if (it >= 1 && it < KIT - 1) STAGE(it + 1, (it + 1) & 1)
        COMPUTE(it & 1)
        if (it < KIT - 1) {
            asm volatile("s_waitcnt vmcnt(0)" ::: "memory");
            __builtin_amdgcn_s_barrier();
        }
    }
    #undef STAGE
    #undef COMPUTE

    // ---- epilogue: masked exp / positive-sim, row-side + col-side partials ----
    __syncthreads();                     // k-loop fully done; smem reusable
    float* rowred = reinterpret_cast<float*>(smem);        // [2 wc][128 row][2]
    float* colred = rowred + 512;                          // [2 wr][128 col][2]

    float cd[4], cs[4];
    #pragma unroll
    for (int fb = 0; fb < 4; ++fb) { cd[fb] = 0.f; cs[fb] = 0.f; }

    #pragma unroll
    for (int fa = 0; fa < 4; ++fa) {
        #pragma unroll
        for (int r = 0; r < 4; ++r) {
            const int row_l = wr * 64 + fa * 16 + grp * 4 + r;
            const int grow  = rowBase + row_l;
            const int lrow  = lbl_row[row_l];
            float dsum = 0.f, ssum = 0.f;
            #pragma unroll
            for (int fb = 0; fb < 4; ++fb) {
                const int col_l = wc * 64 + fb * 16 + lr;
                const float sim = acc[fa][fb][r] * INV_T;
                const float e   = __expf(sim - INV_T);
                const bool  ok  = (colBase + col_l) != grow;   // self (diag only)
                const bool  pos = (lbl_col[col_l] == lrow);
                const float ev  = ok ? e : 0.f;
                const float sv  = (ok && pos) ? sim : 0.f;
                dsum += ev; ssum += sv;
                cd[fb] += ev; cs[fb] += sv;
            }
            #pragma unroll
            for (int m = 8; m >= 1; m >>= 1) {   // reduce over lr (lane bits 0-3)
                dsum += __shfl_xor(dsum, m, 64);
                ssum += __shfl_xor(ssum, m, 64);
            }
            if (lr == 0) {
                rowred[(wc * 128 + row_l) * 2 + 0] = dsum;
                rowred[(wc * 128 + row_l) * 2 + 1] = ssum;
            }
        }
    }
    #pragma unroll
    for (int fb = 0; fb < 4; ++fb) {     // reduce over grp (lane bits 4-5)
        cd[fb] += __shfl_xor(cd[fb], 16, 64);
        cd[fb] += __shfl_xor(cd[fb], 32, 64);
        cs[fb] += __shfl_xor(cs[fb], 16, 64);
        cs[fb] += __shfl_xor(cs[fb], 32, 64);
    }
    if (grp == 0) {
        #pragma unroll
        for (int fb = 0; fb < 4; ++fb) {
            const int col_l = wc * 64 + fb * 16 + lr;
            colred[(wr * 128 + col_l) * 2 + 0] = cd[fb];
            colred[(wr * 128 + col_l) * 2 + 1] = cs[fb];
        }
    }
    __syncthreads();
    if (t < 128) {                       // row-side: combine the two wc halves
        const float d = rowred[t * 2] + rowred[(128 + t) * 2];
        const float s = rowred[t * 2 + 1] + rowred[(128 + t) * 2 + 1];
        part_denom[(size_t)ct * BSZ + rowBase + t] = d;
        part_spos [(size_t)ct * BSZ + rowBase + t] = s;
    } else if (!diag) {                  // col-side: combine the two wr halves
        const int c = t - 128;
        const float d = colred[c * 2] + colred[(128 + c) * 2];
        const float s = colred[c * 2 + 1] + colred[(128 + c) * 2 + 1];
        part_denom[(size_t)rt * BSZ + colBase + c] = d;
        part_spos [(size_t)rt * BSZ + colBase + c] = s;
    }
}

// ---------- kernel 4: per-row finalize ----------
__global__ __launch_bounds__(256) void row_finalize(const float* __restrict__ part_denom,
                                                    const float* __restrict__ part_spos,
                                                    const int* __restrict__ counts,
                                                    const int* __restrict__ labels,
                                                    float* __restrict__ c_row,
                                                    float* __restrict__ v_row) {
    const int row = blockIdx.x * 256 + threadIdx.x;
    float denom = 0.f, spos = 0.f;
    for (int ctile = 0; ctile < 64; ++ctile) {
        denom += part_denom[(size_t)ctile * BSZ + row];
        spos  += part_spos [(size_t)ctile * BSZ + row];
    }
    const int   npos  = counts[labels[row]] - 1;
    const float npf   = (float)npos;
    const float mean  = (spos - npf * INV_T - npf * logf(denom + 1e-12f)) / (npf + 1e-12f);
    const bool  valid = npos > 0;
    c_row[row] = valid ? mean : 0.f;
    v_row[row] = valid ? 1.f : 0.f;
}

// ---------- kernel 5: final scalar reduce ----------
__global__ __launch_bounds__(1024) void final_reduce(const float* __restrict__ c_row,
                                                     const float* __restrict__ v_row,
                                                     float* __restrict__ out) {
    __shared__ float sdata[16], vdata[16];
    const int t = threadIdx.x;
    float s = 0.f, v = 0.f;
    for (int i = t; i < BSZ; i += 1024) { s += c_row[i]; v += v_row[i]; }
    #pragma unroll
    for (int m = 32; m >= 1; m >>= 1) { s += __shfl_xor(s, m, 64); v += __shfl_xor(v, m, 64); }
    if ((t & 63) == 0) { sdata[t >> 6] = s; vdata[t >> 6] = v; }
    __syncthreads();
    if (t == 0) {
        float st = 0.f, vt = 0.f;
        #pragma unroll
        for (int i = 0; i < 16; ++i) { st += sdata[i]; vt += vdata[i]; }
        out[0] = -st / fmaxf(vt, 1.f);
    }
}

extern "C" void kernel_launch(void* const* d_in, const int* in_sizes, int n_in,
                              void* d_out, int out_size, void* d_ws, size_t ws_size,
                              hipStream_t stream) {
    const float* feat   = (const float*)d_in[0];
    const int*   labels = (const int*)d_in[1];
    float*       out    = (float*)d_out;

    char* ws = (char*)d_ws;
    ushort* fnrm       = (ushort*)ws;  ws += (size_t)BSZ * DD * 2;   // 8 MB bf16 normalized
    float*  part_denom = (float*)ws;   ws += (size_t)64 * BSZ * 4;   // 2 MB
    float*  part_spos  = (float*)ws;   ws += (size_t)64 * BSZ * 4;   // 2 MB
    int*    counts     = (int*)ws;     ws += 512;
    float*  c_row      = (float*)ws;   ws += BSZ * 4;
    float*  v_row      = (float*)ws;   ws += BSZ * 4;

    hipLaunchKernelGGL(norm_rows,    dim3(BSZ / 4), dim3(256),  0, stream, feat, fnrm);
    hipLaunchKernelGGL(label_hist,   dim3(1),       dim3(256),  0, stream, labels, counts);
    hipLaunchKernelGGL(supcon_main,  dim3(NBLK),    dim3(256),  0, stream,
                       fnrm, labels, part_denom, part_spos);
    hipLaunchKernelGGL(row_finalize, dim3(BSZ/256), dim3(256),  0, stream,
                       part_denom, part_spos, counts, labels, c_row, v_row);
    hipLaunchKernelGGL(final_reduce, dim3(1),       dim3(1024), 0, stream, c_row, v_row, out);
}